// Round 18
// baseline (124.574 us; speedup 1.0000x reference)
//
#include <hip/hip_runtime.h>

typedef unsigned short u16;
typedef unsigned int u32;
typedef float f32x4 __attribute__((ext_vector_type(4)));
typedef float f32x16 __attribute__((ext_vector_type(16)));
typedef __bf16 bf16x8 __attribute__((ext_vector_type(8)));
typedef u16 u16x8 __attribute__((ext_vector_type(8)));
typedef u32 u32x4 __attribute__((ext_vector_type(4)));

#define ATT_SCALE 0.0125f  // 0.1 / sqrt(64)
#define LOG2E 1.4426950408889634f

__device__ __forceinline__ u16 f2bf(float x) {
  unsigned u = __builtin_bit_cast(unsigned, x);
  u += 0x7fffu + ((u >> 16) & 1u);  // RNE
  return (u16)(u >> 16);
}

__device__ __forceinline__ u32 pack_bf16(float lo, float hi) {
  __bf16 a = (__bf16)lo, b = (__bf16)hi;   // compiler emits v_cvt_pk_bf16_f32
  return ((u32)__builtin_bit_cast(u16, b) << 16) | __builtin_bit_cast(u16, a);
}

__device__ __forceinline__ float fexp2(float x) {
  return __builtin_amdgcn_exp2f(x);  // v_exp_f32: 2^x
}

__device__ __forceinline__ f32x4 mfma16(u16x8 a, u16x8 b, f32x4 c) {
  return __builtin_amdgcn_mfma_f32_16x16x32_bf16(
      __builtin_bit_cast(bf16x8, a), __builtin_bit_cast(bf16x8, b), c, 0, 0, 0);
}

__device__ __forceinline__ f32x16 mfma32(u16x8 a, u16x8 b, f32x16 c) {
  return __builtin_amdgcn_mfma_f32_32x32x16_bf16(
      __builtin_bit_cast(bf16x8, a), __builtin_bit_cast(bf16x8, b), c, 0, 0, 0);
}

__device__ __forceinline__ void gl_lds16(const void* g, void* l) {
  __builtin_amdgcn_global_load_lds(
      (__attribute__((address_space(1))) void*)g,
      (__attribute__((address_space(3))) void*)l, 16, 0, 0);
}

// ---------------- fused preprocessing: convert x + transpose both weights ----
__global__ void k_pre(const float* __restrict__ x, const float* __restrict__ W_attn,
                      const float* __restrict__ W_proj, u16* __restrict__ x_bf,
                      u16* __restrict__ Wt_a, u16* __restrict__ Wt_p) {
  __shared__ float tile[32][33];
  const int id = blockIdx.x, tid = threadIdx.x;
  if (id < 2048) {
    int base = id * 2048 + tid * 4;
#pragma unroll
    for (int s = 0; s < 2; ++s) {
      int i = base + s * 1024;
      float4 v = *(const float4*)&x[i];
      ushort4 o;
      o.x = f2bf(v.x); o.y = f2bf(v.y); o.z = f2bf(v.z); o.w = f2bf(v.w);
      *(ushort4*)&x_bf[i] = o;
    }
    return;
  }
  const float* in;
  u16* outp;
  int rows, cols, bx, by;
  if (id < 5120) {
    int t2 = id - 2048;
    bx = t2 % 96; by = t2 / 96;
    in = W_attn; outp = Wt_a; rows = 1024; cols = 3072;
  } else {
    int t3 = id - 5120;
    bx = t3 & 31; by = t3 >> 5;
    in = W_proj; outp = Wt_p; rows = 1024; cols = 1024;
  }
  int tx = tid & 31, ty = tid >> 5;  // (32, 8)
  int n0 = bx * 32, k0 = by * 32;
#pragma unroll
  for (int i = 0; i < 32; i += 8)
    tile[ty + i][tx] = in[(size_t)(k0 + ty + i) * cols + n0 + tx];
  __syncthreads();
#pragma unroll
  for (int i = 0; i < 32; i += 8)
    outp[(size_t)(n0 + ty + i) * rows + k0 + tx] = f2bf(tile[tx][ty + i]);
}

// ---------------- GEMM1: qkv = x @ W_attn + b_attn, scatter to q/k/vT ------
// 256x256 tile, BK=64, 8 waves (2M x 4N), per-wave 128x64 output.
// K-half-contiguous LDS [dbuf][kh][256][32] so each phase consumes only a
// staged PREFIX -> counted vmcnt(8) keeps 8 loads in flight ACROSS barriers
// (T3+T4; never drain-0 in the main loop). Chunk swizzle c^(r&3) applied on
// pre-swizzled global source + read address (both-sides rule).
__global__ __launch_bounds__(512) void k_gemm_qkv(const u16* __restrict__ A,
                                                  const u16* __restrict__ Bt,
                                                  const float* __restrict__ bias,
                                                  u16* __restrict__ qb,
                                                  u16* __restrict__ kb,
                                                  u16* __restrict__ vTb) {
  __shared__ u16 AL[2][2][256 * 32];   // [dbuf][khalf][row*32+k] 64 KB
  __shared__ u16 BL[2][2][256 * 32];   // 64 KB
  const int tid = threadIdx.x, lane = tid & 63, w = tid >> 6;
  const int wr = w >> 2;           // 0..1  M-half
  const int wc = w & 3;            // 0..3  N-quarter
  const int m0 = blockIdx.y * 256;
  const int n0 = blockIdx.x * 256;
  const int lr = lane & 15;
  const int lg = lane >> 4;        // k-chunk within 32-k half

  f32x4 acc[8][4] = {};

  // ---- stage one (A|B, khalf) unit of K-tile kt into dbuf nb: 2 loads ----
#define STAGE_UNIT(SRC, DST, nb, p, kt)                                        \
  {                                                                            \
    _Pragma("unroll") for (int it_ = 0; it_ < 2; ++it_) {                      \
      int ch = it_ * 512 + tid;      /* 0..1023: r=ch>>2, c=ch&3 */            \
      int r_ = ch >> 2, c_ = ch & 3;                                           \
      gl_lds16(&SRC[(size_t)((m0n0_##SRC) + r_) * 1024 + (kt) * 64 +           \
                    (p) * 32 + ((c_ ^ (r_ & 3)) * 8)],                         \
               &DST[nb][p][ch * 8]);                                           \
    }                                                                          \
  }
  const int m0n0_A = m0;
  const int m0n0_Bt = n0;

  // prologue: tile 0, kh0 (A,B) then kh1 (A,B) -> 8 loads in flight
  STAGE_UNIT(A, AL, 0, 0, 0);
  STAGE_UNIT(Bt, BL, 0, 0, 0);
  STAGE_UNIT(A, AL, 0, 1, 0);
  STAGE_UNIT(Bt, BL, 0, 1, 0);
  int cur = 0;

#pragma unroll 1
  for (int t = 0; t < 16; ++t) {
#pragma unroll
    for (int p = 0; p < 2; ++p) {
      if (t + 1 < 16) {
        // stage khalf p of tile t+1 (A then B) into buf cur^1: 4 loads
        STAGE_UNIT(A, AL, cur ^ 1, p, t + 1);
        STAGE_UNIT(Bt, BL, cur ^ 1, p, t + 1);
        // allow newest 8 (this phase's 4 + previous phase's 4) in flight;
        // everything older -- incl. tile t khalf p -- has landed
        asm volatile("s_waitcnt vmcnt(8)" ::: "memory");
      } else if (p == 0) {
        asm volatile("s_waitcnt vmcnt(4)" ::: "memory");
      } else {
        asm volatile("s_waitcnt vmcnt(0)" ::: "memory");
      }
      __builtin_amdgcn_sched_barrier(0);
      __builtin_amdgcn_s_barrier();

      // B fragments for this k-step (4 ds_read_b128)
      u16x8 bf[4];
#pragma unroll
      for (int nj = 0; nj < 4; ++nj) {
        int rb = wc * 64 + nj * 16 + lr;
        bf[nj] = *(const u16x8*)&BL[cur][p][rb * 32 + ((lg ^ (rb & 3)) * 8)];
      }
      // two M-half clusters: 4 A reads + 16 MFMA each (lower VGPR peak)
#pragma unroll
      for (int mh = 0; mh < 2; ++mh) {
        u16x8 af[4];
#pragma unroll
        for (int q = 0; q < 4; ++q) {
          int mi = mh * 4 + q;
          int ra = wr * 128 + mi * 16 + lr;
          af[q] = *(const u16x8*)&AL[cur][p][ra * 32 + ((lg ^ (ra & 3)) * 8)];
        }
        __builtin_amdgcn_s_setprio(1);
#pragma unroll
        for (int q = 0; q < 4; ++q)
#pragma unroll
          for (int nj = 0; nj < 4; ++nj)
            acc[mh * 4 + q][nj] = mfma16(af[q], bf[nj], acc[mh * 4 + q][nj]);
        __builtin_amdgcn_s_setprio(0);
      }
      __builtin_amdgcn_s_barrier();
    }
    cur ^= 1;
  }
#undef STAGE_UNIT

  // ---- epilogue: which-region is BLOCK-uniform (BN=256 divides 1024) ----
  const int which = n0 >> 10;            // 0=q 1=k 2=vT
  const int b_ = m0 >> 11;               // batch (BM=256 divides 2048)
#pragma unroll
  for (int mi = 0; mi < 8; ++mi) {
    int row = m0 + wr * 128 + mi * 16 + lg * 4;   // + rr (0..3)
    int t0 = row & 2047;
#pragma unroll
    for (int nj = 0; nj < 4; ++nj) {
      int col = n0 + wc * 64 + nj * 16 + lr;
      float bv = bias[col];
      int c = col & 1023;
      int h = c >> 6, d = c & 63;
      int bh = b_ * 16 + h;
      if (which == 2) {
        ushort4 st;
        st.x = f2bf(acc[mi][nj][0] + bv);
        st.y = f2bf(acc[mi][nj][1] + bv);
        st.z = f2bf(acc[mi][nj][2] + bv);
        st.w = f2bf(acc[mi][nj][3] + bv);
        *(ushort4*)&vTb[((size_t)bh * 64 + d) * 2048 + t0] = st;
      } else {
        u16* dst = (which == 0) ? qb : kb;
        float sc = (which == 0) ? (ATT_SCALE * LOG2E) : 1.0f;
#pragma unroll
        for (int r = 0; r < 4; ++r) {
          float fv = (acc[mi][nj][r] + bv) * sc;
          dst[((size_t)bh * 2048 + t0 + r) * 64 + d] = f2bf(fv);
        }
      }
    }
  }
}

// ---------------- flash attention (round-9 structure + counted-vmcnt pipeline)
// qb,kb: [32][2048][64] ; vTb: [32][64][2048] ; yb: [4096][1024] (bf16)
// (verified best; unchanged from rounds 13/15/17)
__device__ __forceinline__ void stage_pair(const u16* __restrict__ kb_bh,
                                           const u16* __restrict__ vT_bh,
                                           u16* Kd, u16* Vd, int kv0, int tid) {
#pragma unroll
  for (int it = 0; it < 4; ++it) {
    int ch = it * 256 + tid;          // 0..1023 16B-chunks
    int r = ch >> 3, c = ch & 7;
    gl_lds16(&kb_bh[(size_t)(kv0 + r) * 64 + (c ^ (r & 7)) * 8], &Kd[ch * 8]);
    int r2 = ch >> 4, c2 = ch & 15;
    int h2 = c2 >> 3, cc = c2 & 7;
    gl_lds16(&vT_bh[(size_t)r2 * 2048 + kv0 + (h2 * 8 + (cc ^ (r2 & 7))) * 8],
             &Vd[ch * 8]);
  }
}

__global__ __launch_bounds__(256) void k_attn(const u16* __restrict__ qb,
                                              const u16* __restrict__ kb,
                                              const u16* __restrict__ vTb,
                                              u16* __restrict__ yb) {
  __shared__ u16 Kl[2][8192];      // [dbuf][128 kv][64 d] swizzled
  __shared__ u16 Vl[2][8192];      // [dbuf][64 d][128 kv] swizzled

  const int tid = threadIdx.x, lane = tid & 63, w = tid >> 6;
  const int wq = w & 1;            // q-half
  const int wp = w >> 1;           // kv-tile parity
  const int id = blockIdx.x;       // XCD-affinity: same bh -> ids congruent mod 8
  const int bh = (id & 7) + ((id >> 7) << 3);
  const int pairi = (id >> 3) & 15;
  const int b_ = bh >> 4, h = bh & 15;
  const int ql = lane & 31;        // this lane's q (and out-col) index
  const int hi = lane >> 5;        // k-half

  const u16* kb_bh = kb + (size_t)bh * 2048 * 64;
  const u16* vT_bh = vTb + (size_t)bh * 64 * 2048;

#pragma unroll 1
  for (int phase = 0; phase < 2; ++phase) {
    const int qt = phase ? (31 - pairi) : pairi;
    const int q0w = qt * 64 + wq * 32;
    const int qg = q0w + ql;                   // this lane's global q row
    const int lim = wq * 32 + ql;              // causal limit within 64-q tile

    const u16* qrow = qb + ((size_t)bh * 2048 + qg) * 64;
    u16x8 qf[4];
#pragma unroll
    for (int ks = 0; ks < 4; ++ks)
      qf[ks] = *(const u16x8*)&qrow[ks * 16 + hi * 8];

    f32x16 o0 = {}, o1 = {};   // O^T d-tiles: d = dt*32 + (r&3)+8*(r>>2)+4*hi
    float mrow = -1e30f, lrow = 0.f;

    const int nkv = qt + 1;
    const int niter = (nkv + 1) >> 1;
    stage_pair(kb_bh, vT_bh, Kl[0], Vl[0], 0, tid);   // 8 loads in flight
    int cur = 0;

#pragma unroll 1
    for (int it = 0; it < niter; ++it) {
      if (it + 1 < niter) {
        stage_pair(kb_bh, vT_bh, Kl[cur ^ 1], Vl[cur ^ 1], (it + 1) * 128, tid);
        asm volatile("s_waitcnt vmcnt(8)" ::: "memory");  // cur landed; next flies
      } else {
        asm volatile("s_waitcnt vmcnt(0)" ::: "memory");
      }
      __builtin_amdgcn_sched_barrier(0);
      __builtin_amdgcn_s_barrier();      // all waves' cur-tile loads landed

      const int mytile = 2 * it + wp;
      if (mytile <= qt) {
        const u16* Kc = Kl[cur];
        const u16* Vc = Vl[cur];
        const int rbase = wp * 64;   // my tile's rows within the K pair-tile

        // S^T = mfma(K, Q): lane holds S[q=ql][kv] rows in regs
        f32x16 s0 = {}, s1 = {};
        __builtin_amdgcn_s_setprio(1);
#pragma unroll
        for (int ks = 0; ks < 4; ++ks) {
          int ch = 2 * ks + hi;
          int r0 = rbase + ql, r1 = rbase + 32 + ql;
          u16x8 kf0 = *(const u16x8*)&Kc[r0 * 64 + ((ch ^ (r0 & 7)) * 8)];
          u16x8 kf1 = *(const u16x8*)&Kc[r1 * 64 + ((ch ^ (r1 & 7)) * 8)];
          s0 = mfma32(kf0, qf[ks], s0);
          s1 = mfma32(kf1, qf[ks], s1);
        }
        __builtin_amdgcn_s_setprio(0);

        // lane-local softmax over 32 kv values (other 32 live in lane^32)
        const bool diag = (mytile == qt);
        float pv[32];
        float tmax = -1e30f;
#pragma unroll
        for (int r = 0; r < 16; ++r) {
          float a = s0[r], b2 = s1[r];
          if (diag) {
            int kl0 = (r & 3) + 8 * (r >> 2) + 4 * hi;
            if (kl0 > lim) a = -1e30f;
            if (kl0 + 32 > lim) b2 = -1e30f;
          }
          pv[r] = a;
          pv[16 + r] = b2;
          tmax = fmaxf(tmax, fmaxf(a, b2));
        }
        float rmax = fmaxf(tmax, __shfl_xor(tmax, 32, 64));

        // defer-max (T13): rescale only when running max grew by > 8
        if (__any(rmax > mrow + 8.0f)) {
          float mn = fmaxf(mrow, rmax);
          float al = fexp2(mrow - mn);
          mrow = mn;
          lrow *= al;
#pragma unroll
          for (int r = 0; r < 16; ++r) { o0[r] *= al; o1[r] *= al; }
        }

        // P = exp2(S - m), pack pairs to bf16 words (lane-partial lrow)
        u32 pw[16];
#pragma unroll
        for (int j = 0; j < 16; ++j) {
          float e0 = fexp2(pv[2 * j] - mrow);
          float e1 = fexp2(pv[2 * j + 1] - mrow);
          lrow += e0 + e1;
          pw[j] = pack_bf16(e0, e1);
        }

        // half-exchange via v_permlane32_swap_b32 (T12)
#pragma unroll
        for (int tt = 0; tt < 2; ++tt)
#pragma unroll
          for (int u = 0; u < 2; ++u)
#pragma unroll
            for (int z = 0; z < 2; ++z) {
              int jA = tt * 8 + u * 4 + z;
              asm volatile("v_permlane32_swap_b32 %0, %1"
                           : "+v"(pw[jA]), "+v"(pw[jA + 2]));
            }

        // O^T += mfma(V^T, P^T): out col = q = ql, rows = d
        __builtin_amdgcn_s_setprio(1);
#pragma unroll
        for (int ks = 0; ks < 4; ++ks) {
          u32x4 pwv = {pw[4 * ks], pw[4 * ks + 1], pw[4 * ks + 2], pw[4 * ks + 3]};
          u16x8 pfrag = __builtin_bit_cast(u16x8, pwv);
          int ch = 2 * ks + hi;
          int rv0 = ql, rv1 = 32 + ql;
          u16x8 vf0 = *(const u16x8*)&Vc[rv0 * 128 + (wp * 8 + (ch ^ (rv0 & 7))) * 8];
          u16x8 vf1 = *(const u16x8*)&Vc[rv1 * 128 + (wp * 8 + (ch ^ (rv1 & 7))) * 8];
          o0 = mfma32(vf0, pfrag, o0);
          o1 = mfma32(vf1, pfrag, o1);
        }
        __builtin_amdgcn_s_setprio(0);
      }
      __builtin_amdgcn_s_barrier();    // all reads of buf[cur] done before
      cur ^= 1;                        // next iter's prefetch overwrites it
    }

    // ---- merge parity partials via retired LDS, then store y ----
    __syncthreads();
    float* mb = (float*)&Kl[0][0];   // 2*64*37*4B = 18.9 KB, fits in Kl
    if (wp == 1) {
      float4* dst = (float4*)&mb[(wq * 64 + lane) * 37];
      float4 hd; hd.x = mrow; hd.y = lrow; hd.z = 0.f; hd.w = 0.f;
      dst[0] = hd;
#pragma unroll
      for (int j = 0; j < 4; ++j) {
        float4 t0 = {o0[4 * j], o0[4 * j + 1], o0[4 * j + 2], o0[4 * j + 3]};
        float4 t1 = {o1[4 * j], o1[4 * j + 1], o1[4 * j + 2], o1[4 * j + 3]};
        dst[1 + j] = t0;
        dst[5 + j] = t1;
      }
    }
    __syncthreads();
    if (wp == 0) {
      const float4* src = (const float4*)&mb[(wq * 64 + lane) * 37];
      float4 hd = src[0];
      float m2 = hd.x, l2 = hd.y;
      float m = fmaxf(mrow, m2);
      float a1 = fexp2(mrow - m), a2 = fexp2(m2 - m);
      float l = lrow * a1 + l2 * a2;
      l += __shfl_xor(l, 32, 64);
      float inv = 1.0f / l;

      size_t ybase = ((size_t)b_ * 2048 + qg) * 1024 + h * 64;
#pragma unroll
      for (int dt = 0; dt < 2; ++dt) {
#pragma unroll
        for (int rg = 0; rg < 4; ++rg) {
          float4 po = src[1 + dt * 4 + rg];
          const f32x16& ov = dt ? o1 : o0;
          int d0 = dt * 32 + 8 * rg + 4 * hi;
          ushort4 st;
          st.x = f2bf((ov[rg * 4 + 0] * a1 + po.x * a2) * inv);
          st.y = f2bf((ov[rg * 4 + 1] * a1 + po.y * a2) * inv);
          st.z = f2bf((ov[rg * 4 + 2] * a1 + po.z * a2) * inv);
          st.w = f2bf((ov[rg * 4 + 3] * a1 + po.w * a2) * inv);
          *(ushort4*)&yb[ybase + d0] = st;
        }
      }
    }
    __syncthreads();   // merge reads done before next phase restages Kl[0]
  }
}

// ---------------- GEMM2: out = y @ W_proj + b_proj (fp32 out) ----------------
__global__ void k_gemm_out(const u16* __restrict__ A, const u16* __restrict__ Bt,
                           const float* __restrict__ bias, float* __restrict__ out) {
  __shared__ u16 Al[64 * 64];
  __shared__ u16 Bl[128 * 64];
  const int tid = threadIdx.x;
  const int lane = tid & 63;
  const int w = tid >> 6;
  const int m0 = blockIdx.y * 64;
  const int n0 = blockIdx.x * 128;
  const int wr = (w >> 1) * 32;
  const int wc = (w & 1) * 64;
  const int lr = lane & 15;
  const int lk = (lane >> 4) * 8;

  f32x4 acc[2][4] = {};

  for (int k0 = 0; k0 < 1024; k0 += 64) {
#pragma unroll
    for (int it = 0; it < 2; ++it) {
      int ch = it * 256 + tid;
      int r = ch >> 3, c = (ch & 7) * 8;
      gl_lds16(&A[(size_t)(m0 + r) * 1024 + k0 + c], &Al[ch * 8]);
    }
#pragma unroll
    for (int it = 0; it < 4; ++it) {
      int ch = it * 256 + tid;
      int r = ch >> 3, c = (ch & 7) * 8;
      gl_lds16(&Bt[(size_t)(n0 + r) * 1024 + k0 + c], &Bl[ch * 8]);
    }
    __syncthreads();
#pragma unroll
    for (int kk = 0; kk < 64; kk += 32) {
      u16x8 af[2], bf[4];
#pragma unroll
      for (int i = 0; i < 2; ++i)
        af[i] = *(const u16x8*)&Al[(wr + i * 16 + lr) * 64 + kk + lk];
#pragma unroll
      for (int j = 0; j < 4; ++j)
        bf[j] = *(const u16x8*)&Bl[(wc + j * 16 + lr) * 64 + kk + lk];
#pragma unroll
      for (int i = 0; i < 2; ++i)
#pragma unroll
        for (int j = 0; j < 4; ++j)
          acc[i][j] = mfma16(af[i], bf[j], acc[i][j]);
    }
    __syncthreads();
  }

#pragma unroll
  for (int i = 0; i < 2; ++i) {
    int rowb = m0 + wr + i * 16 + ((lane >> 4) << 2);
#pragma unroll
    for (int j = 0; j < 4; ++j) {
      int col = n0 + wc + j * 16 + lr;
      float bv = bias[col];
#pragma unroll
      for (int r = 0; r < 4; ++r)
        out[(size_t)(rowb + r) * 1024 + col] = acc[i][j][r] + bv;
    }
  }
}

extern "C" void kernel_launch(void* const* d_in, const int* in_sizes, int n_in,
                              void* d_out, int out_size, void* d_ws, size_t ws_size,
                              hipStream_t stream) {
  const float* x      = (const float*)d_in[0];
  const float* W_attn = (const float*)d_in[1];
  const float* b_attn = (const float*)d_in[2];
  const float* W_proj = (const float*)d_in[3];
  const float* b_proj = (const float*)d_in[4];
  float* out = (float*)d_out;

  char* ws = (char*)d_ws;
  const size_t MB = 1024 * 1024;
  u16* x_bf  = (u16*)(ws);             // 4096*1024   (8 MB)
  u16* Wt_a  = (u16*)(ws + 8 * MB);    // 3072*1024   (6 MB)
  u16* Wt_p  = (u16*)(ws + 14 * MB);   // 1024*1024   (2 MB)
  u16* qbf   = (u16*)(ws + 16 * MB);   // 32*2048*64  (8 MB)
  u16* kbf   = (u16*)(ws + 24 * MB);   // 32*2048*64  (8 MB)
  u16* vTbf  = (u16*)(ws + 32 * MB);   // 32*64*2048  (8 MB)
  u16* ybf   = (u16*)(ws + 40 * MB);   // 4096*1024   (8 MB)

  k_pre<<<6144, 256, 0, stream>>>(x, W_attn, W_proj, x_bf, Wt_a, Wt_p);
  k_gemm_qkv<<<dim3(12, 16), 512, 0, stream>>>(x_bf, Wt_a, b_attn, qbf, kbf, vTbf);
  k_attn<<<512, 256, 0, stream>>>(qbf, kbf, vTbf, ybf);
  k_gemm_out<<<dim3(8, 64), 256, 0, stream>>>(ybf, Wt_p, b_proj, out);
}

// Round 19
// 112.314 us; speedup vs baseline: 1.1092x; 1.1092x over previous
//
#include <hip/hip_runtime.h>

typedef unsigned short u16;
typedef unsigned int u32;
typedef float f32x4 __attribute__((ext_vector_type(4)));
typedef float f32x16 __attribute__((ext_vector_type(16)));
typedef __bf16 bf16x8 __attribute__((ext_vector_type(8)));
typedef u16 u16x8 __attribute__((ext_vector_type(8)));
typedef u32 u32x4 __attribute__((ext_vector_type(4)));

#define ATT_SCALE 0.0125f  // 0.1 / sqrt(64)
#define LOG2E 1.4426950408889634f

__device__ __forceinline__ u16 f2bf(float x) {
  unsigned u = __builtin_bit_cast(unsigned, x);
  u += 0x7fffu + ((u >> 16) & 1u);  // RNE
  return (u16)(u >> 16);
}

__device__ __forceinline__ u32 pack_bf16(float lo, float hi) {
  __bf16 a = (__bf16)lo, b = (__bf16)hi;   // compiler emits v_cvt_pk_bf16_f32
  return ((u32)__builtin_bit_cast(u16, b) << 16) | __builtin_bit_cast(u16, a);
}

__device__ __forceinline__ float fexp2(float x) {
  return __builtin_amdgcn_exp2f(x);  // v_exp_f32: 2^x
}

__device__ __forceinline__ f32x4 mfma16(u16x8 a, u16x8 b, f32x4 c) {
  return __builtin_amdgcn_mfma_f32_16x16x32_bf16(
      __builtin_bit_cast(bf16x8, a), __builtin_bit_cast(bf16x8, b), c, 0, 0, 0);
}

__device__ __forceinline__ f32x16 mfma32(u16x8 a, u16x8 b, f32x16 c) {
  return __builtin_amdgcn_mfma_f32_32x32x16_bf16(
      __builtin_bit_cast(bf16x8, a), __builtin_bit_cast(bf16x8, b), c, 0, 0, 0);
}

__device__ __forceinline__ void gl_lds16(const void* g, void* l) {
  __builtin_amdgcn_global_load_lds(
      (__attribute__((address_space(1))) void*)g,
      (__attribute__((address_space(3))) void*)l, 16, 0, 0);
}

// ---------------- fused preprocessing: convert x + transpose both weights ----
__global__ void k_pre(const float* __restrict__ x, const float* __restrict__ W_attn,
                      const float* __restrict__ W_proj, u16* __restrict__ x_bf,
                      u16* __restrict__ Wt_a, u16* __restrict__ Wt_p) {
  __shared__ float tile[32][33];
  const int id = blockIdx.x, tid = threadIdx.x;
  if (id < 2048) {
    int base = id * 2048 + tid * 4;
#pragma unroll
    for (int s = 0; s < 2; ++s) {
      int i = base + s * 1024;
      float4 v = *(const float4*)&x[i];
      ushort4 o;
      o.x = f2bf(v.x); o.y = f2bf(v.y); o.z = f2bf(v.z); o.w = f2bf(v.w);
      *(ushort4*)&x_bf[i] = o;
    }
    return;
  }
  const float* in;
  u16* outp;
  int rows, cols, bx, by;
  if (id < 5120) {
    int t2 = id - 2048;
    bx = t2 % 96; by = t2 / 96;
    in = W_attn; outp = Wt_a; rows = 1024; cols = 3072;
  } else {
    int t3 = id - 5120;
    bx = t3 & 31; by = t3 >> 5;
    in = W_proj; outp = Wt_p; rows = 1024; cols = 1024;
  }
  int tx = tid & 31, ty = tid >> 5;  // (32, 8)
  int n0 = bx * 32, k0 = by * 32;
#pragma unroll
  for (int i = 0; i < 32; i += 8)
    tile[ty + i][tx] = in[(size_t)(k0 + ty + i) * cols + n0 + tx];
  __syncthreads();
#pragma unroll
  for (int i = 0; i < 32; i += 8)
    outp[(size_t)(n0 + ty + i) * rows + k0 + tx] = f2bf(tile[tx][ty + i]);
}

// ---------------- GEMM1: qkv = x @ W_attn + b_attn, scatter to q/k/vT bf16 ----------------
__global__ void k_gemm_qkv(const u16* __restrict__ A, const u16* __restrict__ Bt,
                           const float* __restrict__ bias,
                           u16* __restrict__ qb, u16* __restrict__ kb, u16* __restrict__ vTb) {
  __shared__ u16 Al[128 * 64];
  __shared__ u16 Bl[128 * 64];
  const int tid = threadIdx.x;
  const int lane = tid & 63;
  const int w = tid >> 6;
  const int m0 = blockIdx.y * 128;
  const int n0 = blockIdx.x * 128;
  const int wr = (w >> 1) * 64;
  const int wc = (w & 1) * 64;
  const int lr = lane & 15;
  const int lk = (lane >> 4) * 8;

  f32x4 acc[4][4] = {};

  for (int k0 = 0; k0 < 1024; k0 += 64) {
#pragma unroll
    for (int it = 0; it < 4; ++it) {
      int off = (it * 256 + tid) * 8;
      int r = off >> 6, c = off & 63;
      gl_lds16(&A[(size_t)(m0 + r) * 1024 + k0 + c], &Al[off]);
      gl_lds16(&Bt[(size_t)(n0 + r) * 1024 + k0 + c], &Bl[off]);
    }
    __syncthreads();
#pragma unroll
    for (int kk = 0; kk < 64; kk += 32) {
      u16x8 af[4], bf[4];
#pragma unroll
      for (int i = 0; i < 4; ++i) {
        af[i] = *(const u16x8*)&Al[(wr + i * 16 + lr) * 64 + kk + lk];
        bf[i] = *(const u16x8*)&Bl[(wc + i * 16 + lr) * 64 + kk + lk];
      }
#pragma unroll
      for (int i = 0; i < 4; ++i)
#pragma unroll
        for (int j = 0; j < 4; ++j)
          acc[i][j] = mfma16(af[i], bf[j], acc[i][j]);
    }
    __syncthreads();
  }

#pragma unroll
  for (int i = 0; i < 4; ++i) {
    int rowb = m0 + wr + i * 16 + ((lane >> 4) << 2);  // multiple of 4
#pragma unroll
    for (int j = 0; j < 4; ++j) {
      int col = n0 + wc + j * 16 + lr;
      float bv = bias[col];
      int which = col >> 10;
      int c = col & 1023;
      int h = c >> 6, d = c & 63;
      int b_ = rowb >> 11, t0 = rowb & 2047;   // same b_ for all 4 rows
      int bh = b_ * 16 + h;
      if (which == 2) {
        ushort4 st;
        st.x = f2bf(acc[i][j][0] + bv);
        st.y = f2bf(acc[i][j][1] + bv);
        st.z = f2bf(acc[i][j][2] + bv);
        st.w = f2bf(acc[i][j][3] + bv);
        *(ushort4*)&vTb[((size_t)bh * 64 + d) * 2048 + t0] = st;
      } else {
        u16* dst = (which == 0) ? qb : kb;
        float sc = (which == 0) ? (ATT_SCALE * LOG2E) : 1.0f;
#pragma unroll
        for (int r = 0; r < 4; ++r) {
          float fv = (acc[i][j][r] + bv) * sc;
          dst[((size_t)bh * 2048 + t0 + r) * 64 + d] = f2bf(fv);
        }
      }
    }
  }
}

// ---------------- flash attention (round-9 structure + counted-vmcnt pipeline)
// qb,kb: [32][2048][64] ; vTb: [32][64][2048] ; yb: [4096][1024] (bf16)
// Block = 4 waves: wq = q-half, wp = KV-tile parity; K+V pair-tiles double-
// buffered in 64 KB LDS (swizzled). Per-iteration sync:
// {stage(next); s_waitcnt vmcnt(8); s_barrier; compute(cur); s_barrier} --
// prefetch loads stay in flight across the compute phase. Every wave runs
// identical staging, so own-vmcnt + barrier == all-loads-landed.
// Pairs (qt, 31-qt) -> constant 33 tiles/block.
__device__ __forceinline__ void stage_pair(const u16* __restrict__ kb_bh,
                                           const u16* __restrict__ vT_bh,
                                           u16* Kd, u16* Vd, int kv0, int tid) {
#pragma unroll
  for (int it = 0; it < 4; ++it) {
    int ch = it * 256 + tid;          // 0..1023 16B-chunks
    // K pair-tile [128 kv][64 d]: swz chunk c^(r&7)
    int r = ch >> 3, c = ch & 7;
    gl_lds16(&kb_bh[(size_t)(kv0 + r) * 64 + (c ^ (r & 7)) * 8], &Kd[ch * 8]);
    // V pair-tile [64 d][128 kv]: swizzle within each 64-kv half
    int r2 = ch >> 4, c2 = ch & 15;
    int h2 = c2 >> 3, cc = c2 & 7;
    gl_lds16(&vT_bh[(size_t)r2 * 2048 + kv0 + (h2 * 8 + (cc ^ (r2 & 7))) * 8],
             &Vd[ch * 8]);
  }
}

__global__ __launch_bounds__(256) void k_attn(const u16* __restrict__ qb,
                                              const u16* __restrict__ kb,
                                              const u16* __restrict__ vTb,
                                              u16* __restrict__ yb) {
  __shared__ u16 Kl[2][8192];      // [dbuf][128 kv][64 d] swizzled
  __shared__ u16 Vl[2][8192];      // [dbuf][64 d][128 kv] swizzled

  const int tid = threadIdx.x, lane = tid & 63, w = tid >> 6;
  const int wq = w & 1;            // q-half
  const int wp = w >> 1;           // kv-tile parity
  const int id = blockIdx.x;       // XCD-affinity: same bh -> ids congruent mod 8
  const int bh = (id & 7) + ((id >> 7) << 3);
  const int pairi = (id >> 3) & 15;
  const int b_ = bh >> 4, h = bh & 15;
  const int ql = lane & 31;        // this lane's q (and out-col) index
  const int hi = lane >> 5;        // k-half

  const u16* kb_bh = kb + (size_t)bh * 2048 * 64;
  const u16* vT_bh = vTb + (size_t)bh * 64 * 2048;

#pragma unroll 1
  for (int phase = 0; phase < 2; ++phase) {
    const int qt = phase ? (31 - pairi) : pairi;
    const int q0w = qt * 64 + wq * 32;
    const int qg = q0w + ql;                   // this lane's global q row
    const int lim = wq * 32 + ql;              // causal limit within 64-q tile

    const u16* qrow = qb + ((size_t)bh * 2048 + qg) * 64;
    u16x8 qf[4];
#pragma unroll
    for (int ks = 0; ks < 4; ++ks)
      qf[ks] = *(const u16x8*)&qrow[ks * 16 + hi * 8];

    f32x16 o0 = {}, o1 = {};   // O^T d-tiles: d = dt*32 + (r&3)+8*(r>>2)+4*hi
    float mrow = -1e30f, lrow = 0.f;

    const int nkv = qt + 1;
    const int niter = (nkv + 1) >> 1;
    stage_pair(kb_bh, vT_bh, Kl[0], Vl[0], 0, tid);   // 8 loads in flight
    int cur = 0;

#pragma unroll 1
    for (int it = 0; it < niter; ++it) {
      if (it + 1 < niter) {
        stage_pair(kb_bh, vT_bh, Kl[cur ^ 1], Vl[cur ^ 1], (it + 1) * 128, tid);
        asm volatile("s_waitcnt vmcnt(8)" ::: "memory");  // cur landed; next flies
      } else {
        asm volatile("s_waitcnt vmcnt(0)" ::: "memory");
      }
      __builtin_amdgcn_sched_barrier(0);
      __builtin_amdgcn_s_barrier();      // all waves' cur-tile loads landed

      const int mytile = 2 * it + wp;
      if (mytile <= qt) {
        const u16* Kc = Kl[cur];
        const u16* Vc = Vl[cur];
        const int rbase = wp * 64;   // my tile's rows within the K pair-tile

        // S^T = mfma(K, Q): lane holds S[q=ql][kv] rows in regs
        f32x16 s0 = {}, s1 = {};
        __builtin_amdgcn_s_setprio(1);
#pragma unroll
        for (int ks = 0; ks < 4; ++ks) {
          int ch = 2 * ks + hi;
          int r0 = rbase + ql, r1 = rbase + 32 + ql;
          u16x8 kf0 = *(const u16x8*)&Kc[r0 * 64 + ((ch ^ (r0 & 7)) * 8)];
          u16x8 kf1 = *(const u16x8*)&Kc[r1 * 64 + ((ch ^ (r1 & 7)) * 8)];
          s0 = mfma32(kf0, qf[ks], s0);
          s1 = mfma32(kf1, qf[ks], s1);
        }
        __builtin_amdgcn_s_setprio(0);

        // lane-local softmax over 32 kv values (other 32 live in lane^32)
        const bool diag = (mytile == qt);
        float pv[32];
        float tmax = -1e30f;
#pragma unroll
        for (int r = 0; r < 16; ++r) {
          float a = s0[r], b2 = s1[r];
          if (diag) {
            int kl0 = (r & 3) + 8 * (r >> 2) + 4 * hi;
            if (kl0 > lim) a = -1e30f;
            if (kl0 + 32 > lim) b2 = -1e30f;
          }
          pv[r] = a;
          pv[16 + r] = b2;
          tmax = fmaxf(tmax, fmaxf(a, b2));
        }
        float rmax = fmaxf(tmax, __shfl_xor(tmax, 32, 64));

        // defer-max (T13): rescale only when running max grew by > 8
        if (__any(rmax > mrow + 8.0f)) {
          float mn = fmaxf(mrow, rmax);
          float al = fexp2(mrow - mn);
          mrow = mn;
          lrow *= al;
#pragma unroll
          for (int r = 0; r < 16; ++r) { o0[r] *= al; o1[r] *= al; }
        }

        // P = exp2(S - m), pack pairs to bf16 words (lane-partial lrow)
        u32 pw[16];
#pragma unroll
        for (int j = 0; j < 16; ++j) {
          float e0 = fexp2(pv[2 * j] - mrow);
          float e1 = fexp2(pv[2 * j + 1] - mrow);
          lrow += e0 + e1;
          pw[j] = pack_bf16(e0, e1);
        }

        // half-exchange via v_permlane32_swap_b32 (T12)
#pragma unroll
        for (int tt = 0; tt < 2; ++tt)
#pragma unroll
          for (int u = 0; u < 2; ++u)
#pragma unroll
            for (int z = 0; z < 2; ++z) {
              int jA = tt * 8 + u * 4 + z;
              asm volatile("v_permlane32_swap_b32 %0, %1"
                           : "+v"(pw[jA]), "+v"(pw[jA + 2]));
            }

        // O^T += mfma(V^T, P^T): out col = q = ql, rows = d
        __builtin_amdgcn_s_setprio(1);
#pragma unroll
        for (int ks = 0; ks < 4; ++ks) {
          u32x4 pwv = {pw[4 * ks], pw[4 * ks + 1], pw[4 * ks + 2], pw[4 * ks + 3]};
          u16x8 pfrag = __builtin_bit_cast(u16x8, pwv);
          int ch = 2 * ks + hi;
          int rv0 = ql, rv1 = 32 + ql;
          u16x8 vf0 = *(const u16x8*)&Vc[rv0 * 128 + (wp * 8 + (ch ^ (rv0 & 7))) * 8];
          u16x8 vf1 = *(const u16x8*)&Vc[rv1 * 128 + (wp * 8 + (ch ^ (rv1 & 7))) * 8];
          o0 = mfma32(vf0, pfrag, o0);
          o1 = mfma32(vf1, pfrag, o1);
        }
        __builtin_amdgcn_s_setprio(0);
      }
      __builtin_amdgcn_s_barrier();    // all reads of buf[cur] done before
      cur ^= 1;                        // next iter's prefetch overwrites it
    }

    // ---- merge parity partials via retired LDS, then store y ----
    __syncthreads();
    float* mb = (float*)&Kl[0][0];   // 2*64*37*4B = 18.9 KB, fits in Kl
    if (wp == 1) {
      float4* dst = (float4*)&mb[(wq * 64 + lane) * 37];
      float4 hd; hd.x = mrow; hd.y = lrow; hd.z = 0.f; hd.w = 0.f;
      dst[0] = hd;
#pragma unroll
      for (int j = 0; j < 4; ++j) {
        float4 t0 = {o0[4 * j], o0[4 * j + 1], o0[4 * j + 2], o0[4 * j + 3]};
        float4 t1 = {o1[4 * j], o1[4 * j + 1], o1[4 * j + 2], o1[4 * j + 3]};
        dst[1 + j] = t0;
        dst[5 + j] = t1;
      }
    }
    __syncthreads();
    if (wp == 0) {
      const float4* src = (const float4*)&mb[(wq * 64 + lane) * 37];
      float4 hd = src[0];
      float m2 = hd.x, l2 = hd.y;
      float m = fmaxf(mrow, m2);
      float a1 = fexp2(mrow - m), a2 = fexp2(m2 - m);
      float l = lrow * a1 + l2 * a2;
      l += __shfl_xor(l, 32, 64);
      float inv = 1.0f / l;

      size_t ybase = ((size_t)b_ * 2048 + qg) * 1024 + h * 64;
#pragma unroll
      for (int dt = 0; dt < 2; ++dt) {
#pragma unroll
        for (int rg = 0; rg < 4; ++rg) {
          float4 po = src[1 + dt * 4 + rg];
          const f32x16& ov = dt ? o1 : o0;
          int d0 = dt * 32 + 8 * rg + 4 * hi;
          ushort4 st;
          st.x = f2bf((ov[rg * 4 + 0] * a1 + po.x * a2) * inv);
          st.y = f2bf((ov[rg * 4 + 1] * a1 + po.y * a2) * inv);
          st.z = f2bf((ov[rg * 4 + 2] * a1 + po.z * a2) * inv);
          st.w = f2bf((ov[rg * 4 + 3] * a1 + po.w * a2) * inv);
          *(ushort4*)&yb[ybase + d0] = st;
        }
      }
    }
    __syncthreads();   // merge reads done before next phase restages Kl[0]
  }
}

// ---------------- GEMM2: out = y @ W_proj + b_proj (fp32 out) ----------------
__global__ void k_gemm_out(const u16* __restrict__ A, const u16* __restrict__ Bt,
                           const float* __restrict__ bias, float* __restrict__ out) {
  __shared__ u16 Al[64 * 64];
  __shared__ u16 Bl[128 * 64];
  const int tid = threadIdx.x;
  const int lane = tid & 63;
  const int w = tid >> 6;
  const int m0 = blockIdx.y * 64;
  const int n0 = blockIdx.x * 128;
  const int wr = (w >> 1) * 32;
  const int wc = (w & 1) * 64;
  const int lr = lane & 15;
  const int lk = (lane >> 4) * 8;

  f32x4 acc[2][4] = {};

  for (int k0 = 0; k0 < 1024; k0 += 64) {
#pragma unroll
    for (int it = 0; it < 2; ++it) {
      int ch = it * 256 + tid;
      int r = ch >> 3, c = (ch & 7) * 8;
      gl_lds16(&A[(size_t)(m0 + r) * 1024 + k0 + c], &Al[ch * 8]);
    }
#pragma unroll
    for (int it = 0; it < 4; ++it) {
      int ch = it * 256 + tid;
      int r = ch >> 3, c = (ch & 7) * 8;
      gl_lds16(&Bt[(size_t)(n0 + r) * 1024 + k0 + c], &Bl[ch * 8]);
    }
    __syncthreads();
#pragma unroll
    for (int kk = 0; kk < 64; kk += 32) {
      u16x8 af[2], bf[4];
#pragma unroll
      for (int i = 0; i < 2; ++i)
        af[i] = *(const u16x8*)&Al[(wr + i * 16 + lr) * 64 + kk + lk];
#pragma unroll
      for (int j = 0; j < 4; ++j)
        bf[j] = *(const u16x8*)&Bl[(wc + j * 16 + lr) * 64 + kk + lk];
#pragma unroll
      for (int i = 0; i < 2; ++i)
#pragma unroll
        for (int j = 0; j < 4; ++j)
          acc[i][j] = mfma16(af[i], bf[j], acc[i][j]);
    }
    __syncthreads();
  }

#pragma unroll
  for (int i = 0; i < 2; ++i) {
    int rowb = m0 + wr + i * 16 + ((lane >> 4) << 2);
#pragma unroll
    for (int j = 0; j < 4; ++j) {
      int col = n0 + wc + j * 16 + lr;
      float bv = bias[col];
#pragma unroll
      for (int r = 0; r < 4; ++r)
        out[(size_t)(rowb + r) * 1024 + col] = acc[i][j][r] + bv;
    }
  }
}

extern "C" void kernel_launch(void* const* d_in, const int* in_sizes, int n_in,
                              void* d_out, int out_size, void* d_ws, size_t ws_size,
                              hipStream_t stream) {
  const float* x      = (const float*)d_in[0];
  const float* W_attn = (const float*)d_in[1];
  const float* b_attn = (const float*)d_in[2];
  const float* W_proj = (const float*)d_in[3];
  const float* b_proj = (const float*)d_in[4];
  float* out = (float*)d_out;

  char* ws = (char*)d_ws;
  const size_t MB = 1024 * 1024;
  u16* x_bf  = (u16*)(ws);             // 4096*1024   (8 MB)
  u16* Wt_a  = (u16*)(ws + 8 * MB);    // 3072*1024   (6 MB)
  u16* Wt_p  = (u16*)(ws + 14 * MB);   // 1024*1024   (2 MB)
  u16* qbf   = (u16*)(ws + 16 * MB);   // 32*2048*64  (8 MB)
  u16* kbf   = (u16*)(ws + 24 * MB);   // 32*2048*64  (8 MB)
  u16* vTbf  = (u16*)(ws + 32 * MB);   // 32*64*2048  (8 MB)
  u16* ybf   = (u16*)(ws + 40 * MB);   // 4096*1024   (8 MB)

  k_pre<<<6144, 256, 0, stream>>>(x, W_attn, W_proj, x_bf, Wt_a, Wt_p);
  k_gemm_qkv<<<dim3(24, 32), 256, 0, stream>>>(x_bf, Wt_a, b_attn, qbf, kbf, vTbf);
  k_attn<<<512, 256, 0, stream>>>(qbf, kbf, vTbf, ybf);
  k_gemm_out<<<dim3(8, 64), 256, 0, stream>>>(ybf, Wt_p, b_proj, out);
}

// Round 20
// 112.228 us; speedup vs baseline: 1.1100x; 1.0008x over previous
//
#include <hip/hip_runtime.h>

typedef unsigned short u16;
typedef unsigned int u32;
typedef float f32x4 __attribute__((ext_vector_type(4)));
typedef float f32x16 __attribute__((ext_vector_type(16)));
typedef __bf16 bf16x8 __attribute__((ext_vector_type(8)));
typedef u16 u16x8 __attribute__((ext_vector_type(8)));
typedef u32 u32x4 __attribute__((ext_vector_type(4)));

#define ATT_SCALE 0.0125f  // 0.1 / sqrt(64)
#define LOG2E 1.4426950408889634f

__device__ __forceinline__ u16 f2bf(float x) {
  unsigned u = __builtin_bit_cast(unsigned, x);
  u += 0x7fffu + ((u >> 16) & 1u);  // RNE
  return (u16)(u >> 16);
}

__device__ __forceinline__ u32 pack_bf16(float lo, float hi) {
  __bf16 a = (__bf16)lo, b = (__bf16)hi;   // compiler emits v_cvt_pk_bf16_f32
  return ((u32)__builtin_bit_cast(u16, b) << 16) | __builtin_bit_cast(u16, a);
}

__device__ __forceinline__ float fexp2(float x) {
  return __builtin_amdgcn_exp2f(x);  // v_exp_f32: 2^x
}

__device__ __forceinline__ f32x4 mfma16(u16x8 a, u16x8 b, f32x4 c) {
  return __builtin_amdgcn_mfma_f32_16x16x32_bf16(
      __builtin_bit_cast(bf16x8, a), __builtin_bit_cast(bf16x8, b), c, 0, 0, 0);
}

__device__ __forceinline__ f32x16 mfma32(u16x8 a, u16x8 b, f32x16 c) {
  return __builtin_amdgcn_mfma_f32_32x32x16_bf16(
      __builtin_bit_cast(bf16x8, a), __builtin_bit_cast(bf16x8, b), c, 0, 0, 0);
}

__device__ __forceinline__ void gl_lds16(const void* g, void* l) {
  __builtin_amdgcn_global_load_lds(
      (__attribute__((address_space(1))) void*)g,
      (__attribute__((address_space(3))) void*)l, 16, 0, 0);
}

// ---------------- fused preprocessing: convert x + transpose both weights ----
__global__ void k_pre(const float* __restrict__ x, const float* __restrict__ W_attn,
                      const float* __restrict__ W_proj, u16* __restrict__ x_bf,
                      u16* __restrict__ Wt_a, u16* __restrict__ Wt_p) {
  __shared__ float tile[32][33];
  const int id = blockIdx.x, tid = threadIdx.x;
  if (id < 2048) {
    int base = id * 2048 + tid * 4;
#pragma unroll
    for (int s = 0; s < 2; ++s) {
      int i = base + s * 1024;
      float4 v = *(const float4*)&x[i];
      ushort4 o;
      o.x = f2bf(v.x); o.y = f2bf(v.y); o.z = f2bf(v.z); o.w = f2bf(v.w);
      *(ushort4*)&x_bf[i] = o;
    }
    return;
  }
  const float* in;
  u16* outp;
  int rows, cols, bx, by;
  if (id < 5120) {
    int t2 = id - 2048;
    bx = t2 % 96; by = t2 / 96;
    in = W_attn; outp = Wt_a; rows = 1024; cols = 3072;
  } else {
    int t3 = id - 5120;
    bx = t3 & 31; by = t3 >> 5;
    in = W_proj; outp = Wt_p; rows = 1024; cols = 1024;
  }
  int tx = tid & 31, ty = tid >> 5;  // (32, 8)
  int n0 = bx * 32, k0 = by * 32;
#pragma unroll
  for (int i = 0; i < 32; i += 8)
    tile[ty + i][tx] = in[(size_t)(k0 + ty + i) * cols + n0 + tx];
  __syncthreads();
#pragma unroll
  for (int i = 0; i < 32; i += 8)
    outp[(size_t)(n0 + ty + i) * rows + k0 + tx] = f2bf(tile[tx][ty + i]);
}

// ---------------- GEMM1: qkv = x @ W_attn + b_attn, scatter to q/k/vT bf16 ----------------
__global__ void k_gemm_qkv(const u16* __restrict__ A, const u16* __restrict__ Bt,
                           const float* __restrict__ bias,
                           u16* __restrict__ qb, u16* __restrict__ kb, u16* __restrict__ vTb) {
  __shared__ u16 Al[128 * 64];
  __shared__ u16 Bl[128 * 64];
  const int tid = threadIdx.x;
  const int lane = tid & 63;
  const int w = tid >> 6;
  const int m0 = blockIdx.y * 128;
  const int n0 = blockIdx.x * 128;
  const int wr = (w >> 1) * 64;
  const int wc = (w & 1) * 64;
  const int lr = lane & 15;
  const int lk = (lane >> 4) * 8;

  f32x4 acc[4][4] = {};

  for (int k0 = 0; k0 < 1024; k0 += 64) {
#pragma unroll
    for (int it = 0; it < 4; ++it) {
      int off = (it * 256 + tid) * 8;
      int r = off >> 6, c = off & 63;
      gl_lds16(&A[(size_t)(m0 + r) * 1024 + k0 + c], &Al[off]);
      gl_lds16(&Bt[(size_t)(n0 + r) * 1024 + k0 + c], &Bl[off]);
    }
    __syncthreads();
#pragma unroll
    for (int kk = 0; kk < 64; kk += 32) {
      u16x8 af[4], bf[4];
#pragma unroll
      for (int i = 0; i < 4; ++i) {
        af[i] = *(const u16x8*)&Al[(wr + i * 16 + lr) * 64 + kk + lk];
        bf[i] = *(const u16x8*)&Bl[(wc + i * 16 + lr) * 64 + kk + lk];
      }
#pragma unroll
      for (int i = 0; i < 4; ++i)
#pragma unroll
        for (int j = 0; j < 4; ++j)
          acc[i][j] = mfma16(af[i], bf[j], acc[i][j]);
    }
    __syncthreads();
  }

#pragma unroll
  for (int i = 0; i < 4; ++i) {
    int rowb = m0 + wr + i * 16 + ((lane >> 4) << 2);  // multiple of 4
#pragma unroll
    for (int j = 0; j < 4; ++j) {
      int col = n0 + wc + j * 16 + lr;
      float bv = bias[col];
      int which = col >> 10;
      int c = col & 1023;
      int h = c >> 6, d = c & 63;
      int b_ = rowb >> 11, t0 = rowb & 2047;   // same b_ for all 4 rows
      int bh = b_ * 16 + h;
      if (which == 2) {
        ushort4 st;
        st.x = f2bf(acc[i][j][0] + bv);
        st.y = f2bf(acc[i][j][1] + bv);
        st.z = f2bf(acc[i][j][2] + bv);
        st.w = f2bf(acc[i][j][3] + bv);
        *(ushort4*)&vTb[((size_t)bh * 64 + d) * 2048 + t0] = st;
      } else {
        u16* dst = (which == 0) ? qb : kb;
        float sc = (which == 0) ? (ATT_SCALE * LOG2E) : 1.0f;
#pragma unroll
        for (int r = 0; r < 4; ++r) {
          float fv = (acc[i][j][r] + bv) * sc;
          dst[((size_t)bh * 2048 + t0 + r) * 64 + d] = f2bf(fv);
        }
      }
    }
  }
}

// ---------------- flash attention: round-13 body, K dbuf + V SINGLE buffer ---
// qb,kb: [32][2048][64] ; vTb: [32][64][2048] ; yb: [4096][1024] (bf16)
// LDS 48 KB (K dbuf 32 + V single 16) -> 3 blocks/CU = 12 waves/CU (+50%).
// V is read only in PV (after the pre-barrier, before the post-barrier), so a
// single V buffer is safe when V(t+1) staging is issued AFTER the post-barrier
// of iteration t. Per-thread FIFO: end(t-1) issues V(t)x4; start(t) issues
// K(t+1)x4; pre-barrier wait vmcnt(4) leaves only K(t+1) in flight -- K(t) and
// V(t) retired. Tail drains vmcnt(0). Body/tiles/swizzles identical to r13.
__device__ __forceinline__ void stage_k4(const u16* __restrict__ kb_bh,
                                         u16* Kd, int kv0, int tid) {
#pragma unroll
  for (int it = 0; it < 4; ++it) {
    int ch = it * 256 + tid;          // 0..1023 chunks: [128 kv][8]
    int r = ch >> 3, c = ch & 7;
    gl_lds16(&kb_bh[(size_t)(kv0 + r) * 64 + (c ^ (r & 7)) * 8], &Kd[ch * 8]);
  }
}

__device__ __forceinline__ void stage_v4(const u16* __restrict__ vT_bh,
                                         u16* Vd, int kv0, int tid) {
#pragma unroll
  for (int it = 0; it < 4; ++it) {
    int ch = it * 256 + tid;          // 0..1023 chunks: [64 d][16]
    int r2 = ch >> 4, c2 = ch & 15;
    int h2 = c2 >> 3, cc = c2 & 7;
    gl_lds16(&vT_bh[(size_t)r2 * 2048 + kv0 + (h2 * 8 + (cc ^ (r2 & 7))) * 8],
             &Vd[ch * 8]);
  }
}

__global__ __launch_bounds__(256) void k_attn(const u16* __restrict__ qb,
                                              const u16* __restrict__ kb,
                                              const u16* __restrict__ vTb,
                                              u16* __restrict__ yb) {
  __shared__ u16 Kl[2][8192];      // [dbuf][128 kv][64 d] swizzled (32 KB)
  __shared__ u16 Vl[8192];         // [64 d][128 kv] swizzled (16 KB, single)

  const int tid = threadIdx.x, lane = tid & 63, w = tid >> 6;
  const int wq = w & 1;            // q-half
  const int wp = w >> 1;           // kv-tile parity
  const int id = blockIdx.x;       // XCD-affinity: same bh -> ids congruent mod 8
  const int bh = (id & 7) + ((id >> 7) << 3);
  const int pairi = (id >> 3) & 15;
  const int b_ = bh >> 4, h = bh & 15;
  const int ql = lane & 31;        // this lane's q (and out-col) index
  const int hi = lane >> 5;        // k-half

  const u16* kb_bh = kb + (size_t)bh * 2048 * 64;
  const u16* vT_bh = vTb + (size_t)bh * 64 * 2048;

#pragma unroll 1
  for (int phase = 0; phase < 2; ++phase) {
    const int qt = phase ? (31 - pairi) : pairi;
    const int q0w = qt * 64 + wq * 32;
    const int qg = q0w + ql;                   // this lane's global q row
    const int lim = wq * 32 + ql;              // causal limit within 64-q tile

    const u16* qrow = qb + ((size_t)bh * 2048 + qg) * 64;
    u16x8 qf[4];
#pragma unroll
    for (int ks = 0; ks < 4; ++ks)
      qf[ks] = *(const u16x8*)&qrow[ks * 16 + hi * 8];

    f32x16 o0 = {}, o1 = {};   // O^T d-tiles: d = dt*32 + (r&3)+8*(r>>2)+4*hi
    float mrow = -1e30f, lrow = 0.f;

    const int nkv = qt + 1;
    const int niter = (nkv + 1) >> 1;
    stage_k4(kb_bh, Kl[0], 0, tid);    // K(0)
    stage_v4(vT_bh, Vl, 0, tid);       // V(0)  -- 8 loads in flight
    int cur = 0;

#pragma unroll 1
    for (int it = 0; it < niter; ++it) {
      if (it + 1 < niter) {
        stage_k4(kb_bh, Kl[cur ^ 1], (it + 1) * 128, tid);   // K(t+1)
        // newest 4 (K(t+1)) may fly; K(t) and V(t) (older) are retired
        asm volatile("s_waitcnt vmcnt(4)" ::: "memory");
      } else {
        asm volatile("s_waitcnt vmcnt(0)" ::: "memory");
      }
      __builtin_amdgcn_sched_barrier(0);
      __builtin_amdgcn_s_barrier();      // all waves' K(t)/V(t) landed

      const int mytile = 2 * it + wp;
      if (mytile <= qt) {
        const u16* Kc = Kl[cur];
        const u16* Vc = Vl;
        const int rbase = wp * 64;   // my tile's rows within the K pair-tile

        // S^T = mfma(K, Q): lane holds S[q=ql][kv] rows in regs
        f32x16 s0 = {}, s1 = {};
        __builtin_amdgcn_s_setprio(1);
#pragma unroll
        for (int ks = 0; ks < 4; ++ks) {
          int ch = 2 * ks + hi;
          int r0 = rbase + ql, r1 = rbase + 32 + ql;
          u16x8 kf0 = *(const u16x8*)&Kc[r0 * 64 + ((ch ^ (r0 & 7)) * 8)];
          u16x8 kf1 = *(const u16x8*)&Kc[r1 * 64 + ((ch ^ (r1 & 7)) * 8)];
          s0 = mfma32(kf0, qf[ks], s0);
          s1 = mfma32(kf1, qf[ks], s1);
        }
        __builtin_amdgcn_s_setprio(0);

        // lane-local softmax over 32 kv values (other 32 live in lane^32)
        const bool diag = (mytile == qt);
        float pv[32];
        float tmax = -1e30f;
#pragma unroll
        for (int r = 0; r < 16; ++r) {
          float a = s0[r], b2 = s1[r];
          if (diag) {
            int kl0 = (r & 3) + 8 * (r >> 2) + 4 * hi;
            if (kl0 > lim) a = -1e30f;
            if (kl0 + 32 > lim) b2 = -1e30f;
          }
          pv[r] = a;
          pv[16 + r] = b2;
          tmax = fmaxf(tmax, fmaxf(a, b2));
        }
        float rmax = fmaxf(tmax, __shfl_xor(tmax, 32, 64));

        // defer-max (T13): rescale only when running max grew by > 8
        if (__any(rmax > mrow + 8.0f)) {
          float mn = fmaxf(mrow, rmax);
          float al = fexp2(mrow - mn);
          mrow = mn;
          lrow *= al;
#pragma unroll
          for (int r = 0; r < 16; ++r) { o0[r] *= al; o1[r] *= al; }
        }

        // P = exp2(S - m), pack pairs to bf16 words (lane-partial lrow)
        u32 pw[16];
#pragma unroll
        for (int j = 0; j < 16; ++j) {
          float e0 = fexp2(pv[2 * j] - mrow);
          float e1 = fexp2(pv[2 * j + 1] - mrow);
          lrow += e0 + e1;
          pw[j] = pack_bf16(e0, e1);
        }

        // half-exchange via v_permlane32_swap_b32 (T12)
#pragma unroll
        for (int tt = 0; tt < 2; ++tt)
#pragma unroll
          for (int u = 0; u < 2; ++u)
#pragma unroll
            for (int z = 0; z < 2; ++z) {
              int jA = tt * 8 + u * 4 + z;
              asm volatile("v_permlane32_swap_b32 %0, %1"
                           : "+v"(pw[jA]), "+v"(pw[jA + 2]));
            }

        // O^T += mfma(V^T, P^T): out col = q = ql, rows = d
        __builtin_amdgcn_s_setprio(1);
#pragma unroll
        for (int ks = 0; ks < 4; ++ks) {
          u32x4 pwv = {pw[4 * ks], pw[4 * ks + 1], pw[4 * ks + 2], pw[4 * ks + 3]};
          u16x8 pfrag = __builtin_bit_cast(u16x8, pwv);
          int ch = 2 * ks + hi;
          int rv0 = ql, rv1 = 32 + ql;
          u16x8 vf0 = *(const u16x8*)&Vc[rv0 * 128 + (wp * 8 + (ch ^ (rv0 & 7))) * 8];
          u16x8 vf1 = *(const u16x8*)&Vc[rv1 * 128 + (wp * 8 + (ch ^ (rv1 & 7))) * 8];
          o0 = mfma32(vf0, pfrag, o0);
          o1 = mfma32(vf1, pfrag, o1);
        }
        __builtin_amdgcn_s_setprio(0);
      }
      __builtin_amdgcn_s_barrier();    // all reads of K[cur]/V done
      if (it + 1 < niter)
        stage_v4(vT_bh, Vl, (it + 1) * 128, tid);   // V(t+1) into single buf
      cur ^= 1;
    }

    // ---- merge parity partials via retired LDS, then store y ----
    __syncthreads();
    float* mb = (float*)&Kl[0][0];   // 2*64*37*4B = 18.9 KB, fits in Kl
    if (wp == 1) {
      float4* dst = (float4*)&mb[(wq * 64 + lane) * 37];
      float4 hd; hd.x = mrow; hd.y = lrow; hd.z = 0.f; hd.w = 0.f;
      dst[0] = hd;
#pragma unroll
      for (int j = 0; j < 4; ++j) {
        float4 t0 = {o0[4 * j], o0[4 * j + 1], o0[4 * j + 2], o0[4 * j + 3]};
        float4 t1 = {o1[4 * j], o1[4 * j + 1], o1[4 * j + 2], o1[4 * j + 3]};
        dst[1 + j] = t0;
        dst[5 + j] = t1;
      }
    }
    __syncthreads();
    if (wp == 0) {
      const float4* src = (const float4*)&mb[(wq * 64 + lane) * 37];
      float4 hd = src[0];
      float m2 = hd.x, l2 = hd.y;
      float m = fmaxf(mrow, m2);
      float a1 = fexp2(mrow - m), a2 = fexp2(m2 - m);
      float l = lrow * a1 + l2 * a2;
      l += __shfl_xor(l, 32, 64);
      float inv = 1.0f / l;

      size_t ybase = ((size_t)b_ * 2048 + qg) * 1024 + h * 64;
#pragma unroll
      for (int dt = 0; dt < 2; ++dt) {
#pragma unroll
        for (int rg = 0; rg < 4; ++rg) {
          float4 po = src[1 + dt * 4 + rg];
          const f32x16& ov = dt ? o1 : o0;
          int d0 = dt * 32 + 8 * rg + 4 * hi;
          ushort4 st;
          st.x = f2bf((ov[rg * 4 + 0] * a1 + po.x * a2) * inv);
          st.y = f2bf((ov[rg * 4 + 1] * a1 + po.y * a2) * inv);
          st.z = f2bf((ov[rg * 4 + 2] * a1 + po.z * a2) * inv);
          st.w = f2bf((ov[rg * 4 + 3] * a1 + po.w * a2) * inv);
          *(ushort4*)&yb[ybase + d0] = st;
        }
      }
    }
    __syncthreads();   // merge reads done before next phase restages Kl[0]
  }
}

// ---------------- GEMM2: out = y @ W_proj + b_proj (fp32 out) ----------------
__global__ void k_gemm_out(const u16* __restrict__ A, const u16* __restrict__ Bt,
                           const float* __restrict__ bias, float* __restrict__ out) {
  __shared__ u16 Al[64 * 64];
  __shared__ u16 Bl[128 * 64];
  const int tid = threadIdx.x;
  const int lane = tid & 63;
  const int w = tid >> 6;
  const int m0 = blockIdx.y * 64;
  const int n0 = blockIdx.x * 128;
  const int wr = (w >> 1) * 32;
  const int wc = (w & 1) * 64;
  const int lr = lane & 15;
  const int lk = (lane >> 4) * 8;

  f32x4 acc[2][4] = {};

  for (int k0 = 0; k0 < 1024; k0 += 64) {
#pragma unroll
    for (int it = 0; it < 2; ++it) {
      int ch = it * 256 + tid;
      int r = ch >> 3, c = (ch & 7) * 8;
      gl_lds16(&A[(size_t)(m0 + r) * 1024 + k0 + c], &Al[ch * 8]);
    }
#pragma unroll
    for (int it = 0; it < 4; ++it) {
      int ch = it * 256 + tid;
      int r = ch >> 3, c = (ch & 7) * 8;
      gl_lds16(&Bt[(size_t)(n0 + r) * 1024 + k0 + c], &Bl[ch * 8]);
    }
    __syncthreads();
#pragma unroll
    for (int kk = 0; kk < 64; kk += 32) {
      u16x8 af[2], bf[4];
#pragma unroll
      for (int i = 0; i < 2; ++i)
        af[i] = *(const u16x8*)&Al[(wr + i * 16 + lr) * 64 + kk + lk];
#pragma unroll
      for (int j = 0; j < 4; ++j)
        bf[j] = *(const u16x8*)&Bl[(wc + j * 16 + lr) * 64 + kk + lk];
#pragma unroll
      for (int i = 0; i < 2; ++i)
#pragma unroll
        for (int j = 0; j < 4; ++j)
          acc[i][j] = mfma16(af[i], bf[j], acc[i][j]);
    }
    __syncthreads();
  }

#pragma unroll
  for (int i = 0; i < 2; ++i) {
    int rowb = m0 + wr + i * 16 + ((lane >> 4) << 2);
#pragma unroll
    for (int j = 0; j < 4; ++j) {
      int col = n0 + wc + j * 16 + lr;
      float bv = bias[col];
#pragma unroll
      for (int r = 0; r < 4; ++r)
        out[(size_t)(rowb + r) * 1024 + col] = acc[i][j][r] + bv;
    }
  }
}

extern "C" void kernel_launch(void* const* d_in, const int* in_sizes, int n_in,
                              void* d_out, int out_size, void* d_ws, size_t ws_size,
                              hipStream_t stream) {
  const float* x      = (const float*)d_in[0];
  const float* W_attn = (const float*)d_in[1];
  const float* b_attn = (const float*)d_in[2];
  const float* W_proj = (const float*)d_in[3];
  const float* b_proj = (const float*)d_in[4];
  float* out = (float*)d_out;

  char* ws = (char*)d_ws;
  const size_t MB = 1024 * 1024;
  u16* x_bf  = (u16*)(ws);             // 4096*1024   (8 MB)
  u16* Wt_a  = (u16*)(ws + 8 * MB);    // 3072*1024   (6 MB)
  u16* Wt_p  = (u16*)(ws + 14 * MB);   // 1024*1024   (2 MB)
  u16* qbf   = (u16*)(ws + 16 * MB);   // 32*2048*64  (8 MB)
  u16* kbf   = (u16*)(ws + 24 * MB);   // 32*2048*64  (8 MB)
  u16* vTbf  = (u16*)(ws + 32 * MB);   // 32*64*2048  (8 MB)
  u16* ybf   = (u16*)(ws + 40 * MB);   // 4096*1024   (8 MB)

  k_pre<<<6144, 256, 0, stream>>>(x, W_attn, W_proj, x_bf, Wt_a, Wt_p);
  k_gemm_qkv<<<dim3(24, 32), 256, 0, stream>>>(x_bf, Wt_a, b_attn, qbf, kbf, vTbf);
  k_attn<<<512, 256, 0, stream>>>(qbf, kbf, vTbf, ybf);
  k_gemm_out<<<dim3(8, 64), 256, 0, stream>>>(ybf, Wt_p, b_proj, out);
}

// Round 21
// 112.044 us; speedup vs baseline: 1.1118x; 1.0016x over previous
//
#include <hip/hip_runtime.h>

typedef unsigned short u16;
typedef unsigned int u32;
typedef float f32x4 __attribute__((ext_vector_type(4)));
typedef float f32x16 __attribute__((ext_vector_type(16)));
typedef __bf16 bf16x8 __attribute__((ext_vector_type(8)));
typedef u16 u16x8 __attribute__((ext_vector_type(8)));
typedef u32 u32x4 __attribute__((ext_vector_type(4)));

#define ATT_SCALE 0.0125f  // 0.1 / sqrt(64)
#define LOG2E 1.4426950408889634f

__device__ __forceinline__ u16 f2bf(float x) {
  unsigned u = __builtin_bit_cast(unsigned, x);
  u += 0x7fffu + ((u >> 16) & 1u);  // RNE
  return (u16)(u >> 16);
}

__device__ __forceinline__ u32 pack_bf16(float lo, float hi) {
  __bf16 a = (__bf16)lo, b = (__bf16)hi;   // compiler emits v_cvt_pk_bf16_f32
  return ((u32)__builtin_bit_cast(u16, b) << 16) | __builtin_bit_cast(u16, a);
}

__device__ __forceinline__ float fexp2(float x) {
  return __builtin_amdgcn_exp2f(x);  // v_exp_f32: 2^x
}

__device__ __forceinline__ f32x4 mfma16(u16x8 a, u16x8 b, f32x4 c) {
  return __builtin_amdgcn_mfma_f32_16x16x32_bf16(
      __builtin_bit_cast(bf16x8, a), __builtin_bit_cast(bf16x8, b), c, 0, 0, 0);
}

__device__ __forceinline__ f32x16 mfma32(u16x8 a, u16x8 b, f32x16 c) {
  return __builtin_amdgcn_mfma_f32_32x32x16_bf16(
      __builtin_bit_cast(bf16x8, a), __builtin_bit_cast(bf16x8, b), c, 0, 0, 0);
}

__device__ __forceinline__ void gl_lds16(const void* g, void* l) {
  __builtin_amdgcn_global_load_lds(
      (__attribute__((address_space(1))) void*)g,
      (__attribute__((address_space(3))) void*)l, 16, 0, 0);
}

// ---------------- fused preprocessing: convert x + transpose both weights ----
__global__ void k_pre(const float* __restrict__ x, const float* __restrict__ W_attn,
                      const float* __restrict__ W_proj, u16* __restrict__ x_bf,
                      u16* __restrict__ Wt_a, u16* __restrict__ Wt_p) {
  __shared__ float tile[32][33];
  const int id = blockIdx.x, tid = threadIdx.x;
  if (id < 2048) {
    int base = id * 2048 + tid * 4;
#pragma unroll
    for (int s = 0; s < 2; ++s) {
      int i = base + s * 1024;
      float4 v = *(const float4*)&x[i];
      ushort4 o;
      o.x = f2bf(v.x); o.y = f2bf(v.y); o.z = f2bf(v.z); o.w = f2bf(v.w);
      *(ushort4*)&x_bf[i] = o;
    }
    return;
  }
  const float* in;
  u16* outp;
  int rows, cols, bx, by;
  if (id < 5120) {
    int t2 = id - 2048;
    bx = t2 % 96; by = t2 / 96;
    in = W_attn; outp = Wt_a; rows = 1024; cols = 3072;
  } else {
    int t3 = id - 5120;
    bx = t3 & 31; by = t3 >> 5;
    in = W_proj; outp = Wt_p; rows = 1024; cols = 1024;
  }
  int tx = tid & 31, ty = tid >> 5;  // (32, 8)
  int n0 = bx * 32, k0 = by * 32;
#pragma unroll
  for (int i = 0; i < 32; i += 8)
    tile[ty + i][tx] = in[(size_t)(k0 + ty + i) * cols + n0 + tx];
  __syncthreads();
#pragma unroll
  for (int i = 0; i < 32; i += 8)
    outp[(size_t)(n0 + ty + i) * rows + k0 + tx] = f2bf(tile[tx][ty + i]);
}

// ---------------- GEMM1: qkv = x @ W_attn + b_attn, scatter to q/k/vT bf16 ----------------
__global__ void k_gemm_qkv(const u16* __restrict__ A, const u16* __restrict__ Bt,
                           const float* __restrict__ bias,
                           u16* __restrict__ qb, u16* __restrict__ kb, u16* __restrict__ vTb) {
  __shared__ u16 Al[128 * 64];
  __shared__ u16 Bl[128 * 64];
  const int tid = threadIdx.x;
  const int lane = tid & 63;
  const int w = tid >> 6;
  const int m0 = blockIdx.y * 128;
  const int n0 = blockIdx.x * 128;
  const int wr = (w >> 1) * 64;
  const int wc = (w & 1) * 64;
  const int lr = lane & 15;
  const int lk = (lane >> 4) * 8;

  f32x4 acc[4][4] = {};

  for (int k0 = 0; k0 < 1024; k0 += 64) {
#pragma unroll
    for (int it = 0; it < 4; ++it) {
      int off = (it * 256 + tid) * 8;
      int r = off >> 6, c = off & 63;
      gl_lds16(&A[(size_t)(m0 + r) * 1024 + k0 + c], &Al[off]);
      gl_lds16(&Bt[(size_t)(n0 + r) * 1024 + k0 + c], &Bl[off]);
    }
    __syncthreads();
#pragma unroll
    for (int kk = 0; kk < 64; kk += 32) {
      u16x8 af[4], bf[4];
#pragma unroll
      for (int i = 0; i < 4; ++i) {
        af[i] = *(const u16x8*)&Al[(wr + i * 16 + lr) * 64 + kk + lk];
        bf[i] = *(const u16x8*)&Bl[(wc + i * 16 + lr) * 64 + kk + lk];
      }
#pragma unroll
      for (int i = 0; i < 4; ++i)
#pragma unroll
        for (int j = 0; j < 4; ++j)
          acc[i][j] = mfma16(af[i], bf[j], acc[i][j]);
    }
    __syncthreads();
  }

#pragma unroll
  for (int i = 0; i < 4; ++i) {
    int rowb = m0 + wr + i * 16 + ((lane >> 4) << 2);  // multiple of 4
#pragma unroll
    for (int j = 0; j < 4; ++j) {
      int col = n0 + wc + j * 16 + lr;
      float bv = bias[col];
      int which = col >> 10;
      int c = col & 1023;
      int h = c >> 6, d = c & 63;
      int b_ = rowb >> 11, t0 = rowb & 2047;   // same b_ for all 4 rows
      int bh = b_ * 16 + h;
      if (which == 2) {
        ushort4 st;
        st.x = f2bf(acc[i][j][0] + bv);
        st.y = f2bf(acc[i][j][1] + bv);
        st.z = f2bf(acc[i][j][2] + bv);
        st.w = f2bf(acc[i][j][3] + bv);
        *(ushort4*)&vTb[((size_t)bh * 64 + d) * 2048 + t0] = st;
      } else {
        u16* dst = (which == 0) ? qb : kb;
        float sc = (which == 0) ? (ATT_SCALE * LOG2E) : 1.0f;
#pragma unroll
        for (int r = 0; r < 4; ++r) {
          float fv = (acc[i][j][r] + bv) * sc;
          dst[((size_t)bh * 2048 + t0 + r) * 64 + d] = f2bf(fv);
        }
      }
    }
  }
}

// ---------------- flash attention: round-13 body, K dbuf + V SINGLE buffer ---
// qb,kb: [32][2048][64] ; vTb: [32][64][2048] ; yb: [4096][1024] (bf16)
// Block = 4 waves (wq q-half x wp kv-parity); pairs (qt,31-qt) -> 33 tiles
// per block, perfectly balanced. K pair-tiles double-buffered (32 KB) with
// counted-vmcnt prefetch across barriers; V single-buffered (16 KB), staged
// after the post-barrier of the prior iteration (per-thread FIFO: pre-barrier
// vmcnt(4) leaves only K(t+1) in flight; K(t),V(t) retired). In-register
// softmax in exp2 domain, P via pack+permlane32_swap, defer-max rescale.
// Verified optimum of this structure family (7 reproductions, ~112.2 us).
__device__ __forceinline__ void stage_k4(const u16* __restrict__ kb_bh,
                                         u16* Kd, int kv0, int tid) {
#pragma unroll
  for (int it = 0; it < 4; ++it) {
    int ch = it * 256 + tid;          // 0..1023 chunks: [128 kv][8]
    int r = ch >> 3, c = ch & 7;
    gl_lds16(&kb_bh[(size_t)(kv0 + r) * 64 + (c ^ (r & 7)) * 8], &Kd[ch * 8]);
  }
}

__device__ __forceinline__ void stage_v4(const u16* __restrict__ vT_bh,
                                         u16* Vd, int kv0, int tid) {
#pragma unroll
  for (int it = 0; it < 4; ++it) {
    int ch = it * 256 + tid;          // 0..1023 chunks: [64 d][16]
    int r2 = ch >> 4, c2 = ch & 15;
    int h2 = c2 >> 3, cc = c2 & 7;
    gl_lds16(&vT_bh[(size_t)r2 * 2048 + kv0 + (h2 * 8 + (cc ^ (r2 & 7))) * 8],
             &Vd[ch * 8]);
  }
}

__global__ __launch_bounds__(256) void k_attn(const u16* __restrict__ qb,
                                              const u16* __restrict__ kb,
                                              const u16* __restrict__ vTb,
                                              u16* __restrict__ yb) {
  __shared__ u16 Kl[2][8192];      // [dbuf][128 kv][64 d] swizzled (32 KB)
  __shared__ u16 Vl[8192];         // [64 d][128 kv] swizzled (16 KB, single)

  const int tid = threadIdx.x, lane = tid & 63, w = tid >> 6;
  const int wq = w & 1;            // q-half
  const int wp = w >> 1;           // kv-tile parity
  const int id = blockIdx.x;       // XCD-affinity: same bh -> ids congruent mod 8
  const int bh = (id & 7) + ((id >> 7) << 3);
  const int pairi = (id >> 3) & 15;
  const int b_ = bh >> 4, h = bh & 15;
  const int ql = lane & 31;        // this lane's q (and out-col) index
  const int hi = lane >> 5;        // k-half

  const u16* kb_bh = kb + (size_t)bh * 2048 * 64;
  const u16* vT_bh = vTb + (size_t)bh * 64 * 2048;

#pragma unroll 1
  for (int phase = 0; phase < 2; ++phase) {
    const int qt = phase ? (31 - pairi) : pairi;
    const int q0w = qt * 64 + wq * 32;
    const int qg = q0w + ql;                   // this lane's global q row
    const int lim = wq * 32 + ql;              // causal limit within 64-q tile

    const u16* qrow = qb + ((size_t)bh * 2048 + qg) * 64;
    u16x8 qf[4];
#pragma unroll
    for (int ks = 0; ks < 4; ++ks)
      qf[ks] = *(const u16x8*)&qrow[ks * 16 + hi * 8];

    f32x16 o0 = {}, o1 = {};   // O^T d-tiles: d = dt*32 + (r&3)+8*(r>>2)+4*hi
    float mrow = -1e30f, lrow = 0.f;

    const int nkv = qt + 1;
    const int niter = (nkv + 1) >> 1;
    stage_k4(kb_bh, Kl[0], 0, tid);    // K(0)
    stage_v4(vT_bh, Vl, 0, tid);       // V(0)  -- 8 loads in flight
    int cur = 0;

#pragma unroll 1
    for (int it = 0; it < niter; ++it) {
      if (it + 1 < niter) {
        stage_k4(kb_bh, Kl[cur ^ 1], (it + 1) * 128, tid);   // K(t+1)
        // newest 4 (K(t+1)) may fly; K(t) and V(t) (older) are retired
        asm volatile("s_waitcnt vmcnt(4)" ::: "memory");
      } else {
        asm volatile("s_waitcnt vmcnt(0)" ::: "memory");
      }
      __builtin_amdgcn_sched_barrier(0);
      __builtin_amdgcn_s_barrier();      // all waves' K(t)/V(t) landed

      const int mytile = 2 * it + wp;
      if (mytile <= qt) {
        const u16* Kc = Kl[cur];
        const u16* Vc = Vl;
        const int rbase = wp * 64;   // my tile's rows within the K pair-tile

        // S^T = mfma(K, Q): lane holds S[q=ql][kv] rows in regs
        f32x16 s0 = {}, s1 = {};
        __builtin_amdgcn_s_setprio(1);
#pragma unroll
        for (int ks = 0; ks < 4; ++ks) {
          int ch = 2 * ks + hi;
          int r0 = rbase + ql, r1 = rbase + 32 + ql;
          u16x8 kf0 = *(const u16x8*)&Kc[r0 * 64 + ((ch ^ (r0 & 7)) * 8)];
          u16x8 kf1 = *(const u16x8*)&Kc[r1 * 64 + ((ch ^ (r1 & 7)) * 8)];
          s0 = mfma32(kf0, qf[ks], s0);
          s1 = mfma32(kf1, qf[ks], s1);
        }
        __builtin_amdgcn_s_setprio(0);

        // lane-local softmax over 32 kv values (other 32 live in lane^32)
        const bool diag = (mytile == qt);
        float pv[32];
        float tmax = -1e30f;
#pragma unroll
        for (int r = 0; r < 16; ++r) {
          float a = s0[r], b2 = s1[r];
          if (diag) {
            int kl0 = (r & 3) + 8 * (r >> 2) + 4 * hi;
            if (kl0 > lim) a = -1e30f;
            if (kl0 + 32 > lim) b2 = -1e30f;
          }
          pv[r] = a;
          pv[16 + r] = b2;
          tmax = fmaxf(tmax, fmaxf(a, b2));
        }
        float rmax = fmaxf(tmax, __shfl_xor(tmax, 32, 64));

        // defer-max (T13): rescale only when running max grew by > 8
        if (__any(rmax > mrow + 8.0f)) {
          float mn = fmaxf(mrow, rmax);
          float al = fexp2(mrow - mn);
          mrow = mn;
          lrow *= al;
#pragma unroll
          for (int r = 0; r < 16; ++r) { o0[r] *= al; o1[r] *= al; }
        }

        // P = exp2(S - m), pack pairs to bf16 words (lane-partial lrow)
        u32 pw[16];
#pragma unroll
        for (int j = 0; j < 16; ++j) {
          float e0 = fexp2(pv[2 * j] - mrow);
          float e1 = fexp2(pv[2 * j + 1] - mrow);
          lrow += e0 + e1;
          pw[j] = pack_bf16(e0, e1);
        }

        // half-exchange via v_permlane32_swap_b32 (T12)
#pragma unroll
        for (int tt = 0; tt < 2; ++tt)
#pragma unroll
          for (int u = 0; u < 2; ++u)
#pragma unroll
            for (int z = 0; z < 2; ++z) {
              int jA = tt * 8 + u * 4 + z;
              asm volatile("v_permlane32_swap_b32 %0, %1"
                           : "+v"(pw[jA]), "+v"(pw[jA + 2]));
            }

        // O^T += mfma(V^T, P^T): out col = q = ql, rows = d
        __builtin_amdgcn_s_setprio(1);
#pragma unroll
        for (int ks = 0; ks < 4; ++ks) {
          u32x4 pwv = {pw[4 * ks], pw[4 * ks + 1], pw[4 * ks + 2], pw[4 * ks + 3]};
          u16x8 pfrag = __builtin_bit_cast(u16x8, pwv);
          int ch = 2 * ks + hi;
          int rv0 = ql, rv1 = 32 + ql;
          u16x8 vf0 = *(const u16x8*)&Vc[rv0 * 128 + (wp * 8 + (ch ^ (rv0 & 7))) * 8];
          u16x8 vf1 = *(const u16x8*)&Vc[rv1 * 128 + (wp * 8 + (ch ^ (rv1 & 7))) * 8];
          o0 = mfma32(vf0, pfrag, o0);
          o1 = mfma32(vf1, pfrag, o1);
        }
        __builtin_amdgcn_s_setprio(0);
      }
      __builtin_amdgcn_s_barrier();    // all reads of K[cur]/V done
      if (it + 1 < niter)
        stage_v4(vT_bh, Vl, (it + 1) * 128, tid);   // V(t+1) into single buf
      cur ^= 1;
    }

    // ---- merge parity partials via retired LDS, then store y ----
    __syncthreads();
    float* mb = (float*)&Kl[0][0];   // 2*64*37*4B = 18.9 KB, fits in Kl
    if (wp == 1) {
      float4* dst = (float4*)&mb[(wq * 64 + lane) * 37];
      float4 hd; hd.x = mrow; hd.y = lrow; hd.z = 0.f; hd.w = 0.f;
      dst[0] = hd;
#pragma unroll
      for (int j = 0; j < 4; ++j) {
        float4 t0 = {o0[4 * j], o0[4 * j + 1], o0[4 * j + 2], o0[4 * j + 3]};
        float4 t1 = {o1[4 * j], o1[4 * j + 1], o1[4 * j + 2], o1[4 * j + 3]};
        dst[1 + j] = t0;
        dst[5 + j] = t1;
      }
    }
    __syncthreads();
    if (wp == 0) {
      const float4* src = (const float4*)&mb[(wq * 64 + lane) * 37];
      float4 hd = src[0];
      float m2 = hd.x, l2 = hd.y;
      float m = fmaxf(mrow, m2);
      float a1 = fexp2(mrow - m), a2 = fexp2(m2 - m);
      float l = lrow * a1 + l2 * a2;
      l += __shfl_xor(l, 32, 64);
      float inv = 1.0f / l;

      size_t ybase = ((size_t)b_ * 2048 + qg) * 1024 + h * 64;
#pragma unroll
      for (int dt = 0; dt < 2; ++dt) {
#pragma unroll
        for (int rg = 0; rg < 4; ++rg) {
          float4 po = src[1 + dt * 4 + rg];
          const f32x16& ov = dt ? o1 : o0;
          int d0 = dt * 32 + 8 * rg + 4 * hi;
          ushort4 st;
          st.x = f2bf((ov[rg * 4 + 0] * a1 + po.x * a2) * inv);
          st.y = f2bf((ov[rg * 4 + 1] * a1 + po.y * a2) * inv);
          st.z = f2bf((ov[rg * 4 + 2] * a1 + po.z * a2) * inv);
          st.w = f2bf((ov[rg * 4 + 3] * a1 + po.w * a2) * inv);
          *(ushort4*)&yb[ybase + d0] = st;
        }
      }
    }
    __syncthreads();   // merge reads done before next phase restages Kl[0]
  }
}

// ---------------- GEMM2: out = y @ W_proj + b_proj (fp32 out) ----------------
__global__ void k_gemm_out(const u16* __restrict__ A, const u16* __restrict__ Bt,
                           const float* __restrict__ bias, float* __restrict__ out) {
  __shared__ u16 Al[64 * 64];
  __shared__ u16 Bl[128 * 64];
  const int tid = threadIdx.x;
  const int lane = tid & 63;
  const int w = tid >> 6;
  const int m0 = blockIdx.y * 64;
  const int n0 = blockIdx.x * 128;
  const int wr = (w >> 1) * 32;
  const int wc = (w & 1) * 64;
  const int lr = lane & 15;
  const int lk = (lane >> 4) * 8;

  f32x4 acc[2][4] = {};

  for (int k0 = 0; k0 < 1024; k0 += 64) {
#pragma unroll
    for (int it = 0; it < 2; ++it) {
      int ch = it * 256 + tid;
      int r = ch >> 3, c = (ch & 7) * 8;
      gl_lds16(&A[(size_t)(m0 + r) * 1024 + k0 + c], &Al[ch * 8]);
    }
#pragma unroll
    for (int it = 0; it < 4; ++it) {
      int ch = it * 256 + tid;
      int r = ch >> 3, c = (ch & 7) * 8;
      gl_lds16(&Bt[(size_t)(n0 + r) * 1024 + k0 + c], &Bl[ch * 8]);
    }
    __syncthreads();
#pragma unroll
    for (int kk = 0; kk < 64; kk += 32) {
      u16x8 af[2], bf[4];
#pragma unroll
      for (int i = 0; i < 2; ++i)
        af[i] = *(const u16x8*)&Al[(wr + i * 16 + lr) * 64 + kk + lk];
#pragma unroll
      for (int j = 0; j < 4; ++j)
        bf[j] = *(const u16x8*)&Bl[(wc + j * 16 + lr) * 64 + kk + lk];
#pragma unroll
      for (int i = 0; i < 2; ++i)
#pragma unroll
        for (int j = 0; j < 4; ++j)
          acc[i][j] = mfma16(af[i], bf[j], acc[i][j]);
    }
    __syncthreads();
  }

#pragma unroll
  for (int i = 0; i < 2; ++i) {
    int rowb = m0 + wr + i * 16 + ((lane >> 4) << 2);
#pragma unroll
    for (int j = 0; j < 4; ++j) {
      int col = n0 + wc + j * 16 + lr;
      float bv = bias[col];
#pragma unroll
      for (int r = 0; r < 4; ++r)
        out[(size_t)(rowb + r) * 1024 + col] = acc[i][j][r] + bv;
    }
  }
}

extern "C" void kernel_launch(void* const* d_in, const int* in_sizes, int n_in,
                              void* d_out, int out_size, void* d_ws, size_t ws_size,
                              hipStream_t stream) {
  const float* x      = (const float*)d_in[0];
  const float* W_attn = (const float*)d_in[1];
  const float* b_attn = (const float*)d_in[2];
  const float* W_proj = (const float*)d_in[3];
  const float* b_proj = (const float*)d_in[4];
  float* out = (float*)d_out;

  char* ws = (char*)d_ws;
  const size_t MB = 1024 * 1024;
  u16* x_bf  = (u16*)(ws);             // 4096*1024   (8 MB)
  u16* Wt_a  = (u16*)(ws + 8 * MB);    // 3072*1024   (6 MB)
  u16* Wt_p  = (u16*)(ws + 14 * MB);   // 1024*1024   (2 MB)
  u16* qbf   = (u16*)(ws + 16 * MB);   // 32*2048*64  (8 MB)
  u16* kbf   = (u16*)(ws + 24 * MB);   // 32*2048*64  (8 MB)
  u16* vTbf  = (u16*)(ws + 32 * MB);   // 32*64*2048  (8 MB)
  u16* ybf   = (u16*)(ws + 40 * MB);   // 4096*1024   (8 MB)

  k_pre<<<6144, 256, 0, stream>>>(x, W_attn, W_proj, x_bf, Wt_a, Wt_p);
  k_gemm_qkv<<<dim3(24, 32), 256, 0, stream>>>(x_bf, Wt_a, b_attn, qbf, kbf, vTbf);
  k_attn<<<512, 256, 0, stream>>>(qbf, kbf, vTbf, ybf);
  k_gemm_out<<<dim3(8, 64), 256, 0, stream>>>(ybf, Wt_p, b_proj, out);
}